// Round 1
// baseline (100.890 us; speedup 1.0000x reference)
//
#include <hip/hip_runtime.h>

#define NT 2000000
#define NE 20000
#define NTILES (NT / 64)   // 31250, exact

using bf16x8 = __attribute__((ext_vector_type(8))) __bf16;
using bf16x4 = __attribute__((ext_vector_type(4))) __bf16;
using f32x4  = __attribute__((ext_vector_type(4))) float;
using fvec4  = __attribute__((ext_vector_type(4))) float;

// Load 8 consecutive f32 weights, split into hi/lo bf16 (kills systematic
// weight-rounding error; lo term costs one extra MFMA).
__device__ __forceinline__ void load_bsplit(const float* __restrict__ p,
                                            bf16x8& hi, bf16x8& lo) {
    fvec4 a = *(const fvec4*)p;
    fvec4 b = *(const fvec4*)(p + 4);
#pragma unroll
    for (int e = 0; e < 4; e++) {
        float v  = a[e];
        __bf16 h = (__bf16)v;
        hi[e]    = h;
        lo[e]    = (__bf16)(v - (float)h);
        float v2  = b[e];
        __bf16 h2 = (__bf16)v2;
        hi[e + 4] = h2;
        lo[e + 4] = (__bf16)(v2 - (float)h2);
    }
}

// ---------------- K1: fused phi1 (2 layers) + jagged segment-sum ----------------
__global__ __launch_bounds__(256, 2) void k1_phi1(
    const float* __restrict__ values, const int* __restrict__ seg,
    const float* __restrict__ w0, const float* __restrict__ b0,
    const float* __restrict__ w1, const float* __restrict__ b1,
    float* __restrict__ ev) {
    // per-wave 64x64 bf16 h2 tile, transposed [j][p] with XOR swizzle
    __shared__ __align__(16) __bf16 h2t[4][4096];

    const int tid = threadIdx.x;
    const int w   = tid >> 6;
    const int l   = tid & 63;
    const int l15 = l & 15;
    const int l4  = l >> 4;

    // B fragments for W1 (hi/lo): B[k][j] = W1[j][k]; lane holds col j=16jf+l15,
    // k = 32kf + 8*l4 + e  (8 consecutive -> two float4 from row j)
    bf16x8 Bh[2][4], Bl[2][4];
#pragma unroll
    for (int kf = 0; kf < 2; kf++)
#pragma unroll
        for (int jf = 0; jf < 4; jf++)
            load_bsplit(w1 + (jf * 16 + l15) * 64 + kf * 32 + l4 * 8,
                        Bh[kf][jf], Bl[kf][jf]);

    // layer-1 weights for this lane's 8 k's per kf
    float w0q[2][8], b0q[2][8];
#pragma unroll
    for (int kf = 0; kf < 2; kf++) {
        const int kb = kf * 32 + l4 * 8;
        fvec4 wa = *(const fvec4*)(w0 + kb);
        fvec4 wb = *(const fvec4*)(w0 + kb + 4);
        fvec4 ba = *(const fvec4*)(b0 + kb);
        fvec4 bb = *(const fvec4*)(b0 + kb + 4);
#pragma unroll
        for (int e = 0; e < 4; e++) {
            w0q[kf][e]     = wa[e];
            w0q[kf][e + 4] = wb[e];
            b0q[kf][e]     = ba[e];
            b0q[kf][e + 4] = bb[e];
        }
    }
    float biasj[4];
#pragma unroll
    for (int jf = 0; jf < 4; jf++) biasj[jf] = b1[jf * 16 + l15];

    __bf16* my = h2t[w];

    for (int tile = blockIdx.x * 4 + w; tile < NTILES; tile += gridDim.x * 4) {
        const int base = tile * 64;
        const int s_l  = seg[base + l];       // lane l holds seg of particle l
        float vp[4];
#pragma unroll
        for (int pf = 0; pf < 4; pf++) vp[pf] = values[base + pf * 16 + l15];

        f32x4 acc[4][4];
#pragma unroll
        for (int pf = 0; pf < 4; pf++)
#pragma unroll
            for (int jf = 0; jf < 4; jf++)
#pragma unroll
                for (int r = 0; r < 4; r++) acc[pf][jf][r] = biasj[jf];

#pragma unroll
        for (int kf = 0; kf < 2; kf++) {
            // build A fragments in-register: h = relu(v*w0+b0), bf16
            bf16x8 A[4];
#pragma unroll
            for (int pf = 0; pf < 4; pf++) {
#pragma unroll
                for (int e = 0; e < 8; e++) {
                    float h = fmaxf(vp[pf] * w0q[kf][e] + b0q[kf][e], 0.f);
                    A[pf][e] = (__bf16)h;
                }
            }
#pragma unroll
            for (int pf = 0; pf < 4; pf++)
#pragma unroll
                for (int jf = 0; jf < 4; jf++)
                    acc[pf][jf] = __builtin_amdgcn_mfma_f32_16x16x32_bf16(
                        A[pf], Bh[kf][jf], acc[pf][jf], 0, 0, 0);
#pragma unroll
            for (int pf = 0; pf < 4; pf++)
#pragma unroll
                for (int jf = 0; jf < 4; jf++)
                    acc[pf][jf] = __builtin_amdgcn_mfma_f32_16x16x32_bf16(
                        A[pf], Bl[kf][jf], acc[pf][jf], 0, 0, 0);
        }

        // relu + store transposed [j][p^swz] as bf16 (b64 per fragment)
#pragma unroll
        for (int pf = 0; pf < 4; pf++)
#pragma unroll
            for (int jf = 0; jf < 4; jf++) {
                const int j  = jf * 16 + l15;
                const int p0 = pf * 16 + l4 * 4;   // 4 consecutive particles
                bf16x4 st;
#pragma unroll
                for (int r = 0; r < 4; r++)
                    st[r] = (__bf16)fmaxf(acc[pf][jf][r], 0.f);
                *(bf16x4*)(my + j * 64 + (p0 ^ ((j & 7) << 3))) = st;
            }

        // segmented reduce: lane l owns feature j=l; seg boundaries are
        // wave-uniform (readlane) -> scalar branches, ~1.6 flushes/tile
        float accr = 0.f;
        int   cur  = __builtin_amdgcn_readlane(s_l, 0);
#pragma unroll
        for (int m = 0; m < 8; m++) {
            bf16x8 hv = *(const bf16x8*)(my + l * 64 + ((m * 8) ^ ((l & 7) << 3)));
#pragma unroll
            for (int i = 0; i < 8; i++) {
                const int sp = __builtin_amdgcn_readlane(s_l, m * 8 + i);
                if (sp != cur) {
                    atomicAdd(ev + cur * 64 + l, accr);
                    accr = 0.f;
                    cur  = sp;
                }
                accr += (float)hv[i];
            }
        }
        atomicAdd(ev + cur * 64 + l, accr);
    }
}

// ---------------- K2: rho1 + o1 + phi2 (5 fused 64x64 layers) + event-sum ----------------
__global__ __launch_bounds__(256, 2) void k2_events(
    const float* __restrict__ ev,
    const float* __restrict__ W0, const float* __restrict__ B0,
    const float* __restrict__ W1, const float* __restrict__ B1,
    const float* __restrict__ W2, const float* __restrict__ B2,
    const float* __restrict__ W3, const float* __restrict__ B3,
    const float* __restrict__ W4, const float* __restrict__ B4,
    float* __restrict__ s2) {
    __shared__ __align__(16) __bf16 xt[4][64 * 72];   // [e][k], stride 72
    const int tid = threadIdx.x;
    const int w   = tid >> 6;
    const int l   = tid & 63;
    const int l15 = l & 15;
    const int l4  = l >> 4;
    const int ebase = blockIdx.x * 256 + w * 64;

    const float* Ws[5] = {W0, W1, W2, W3, W4};
    const float* Bs[5] = {B0, B1, B2, B3, B4};

    // A fragments from ev (layer-0 input), masked for e >= NE
    bf16x8 A[4][2];
#pragma unroll
    for (int pf = 0; pf < 4; pf++) {
        const int e = ebase + pf * 16 + l15;
#pragma unroll
        for (int kf = 0; kf < 2; kf++) {
            bf16x8 a;
            if (e < NE) {
                const float* p = ev + (size_t)e * 64 + kf * 32 + l4 * 8;
                fvec4 x = *(const fvec4*)p;
                fvec4 y = *(const fvec4*)(p + 4);
#pragma unroll
                for (int e2 = 0; e2 < 4; e2++) {
                    a[e2]     = (__bf16)x[e2];
                    a[e2 + 4] = (__bf16)y[e2];
                }
            } else {
#pragma unroll
                for (int e2 = 0; e2 < 8; e2++) a[e2] = (__bf16)0.f;
            }
            A[pf][kf] = a;
        }
    }

    __bf16* my = xt[w];

#pragma unroll
    for (int L = 0; L < 5; L++) {
        bf16x8 Bh[2][4], Bl[2][4];
#pragma unroll
        for (int kf = 0; kf < 2; kf++)
#pragma unroll
            for (int jf = 0; jf < 4; jf++)
                load_bsplit(Ws[L] + (jf * 16 + l15) * 64 + kf * 32 + l4 * 8,
                            Bh[kf][jf], Bl[kf][jf]);

        f32x4 acc[4][4];
#pragma unroll
        for (int jf = 0; jf < 4; jf++) {
            const float bj = Bs[L][jf * 16 + l15];
#pragma unroll
            for (int pf = 0; pf < 4; pf++)
#pragma unroll
                for (int r = 0; r < 4; r++) acc[pf][jf][r] = bj;
        }
#pragma unroll
        for (int kf = 0; kf < 2; kf++)
#pragma unroll
            for (int pf = 0; pf < 4; pf++)
#pragma unroll
                for (int jf = 0; jf < 4; jf++)
                    acc[pf][jf] = __builtin_amdgcn_mfma_f32_16x16x32_bf16(
                        A[pf][kf], Bh[kf][jf], acc[pf][jf], 0, 0, 0);
#pragma unroll
        for (int kf = 0; kf < 2; kf++)
#pragma unroll
            for (int pf = 0; pf < 4; pf++)
#pragma unroll
                for (int jf = 0; jf < 4; jf++)
                    acc[pf][jf] = __builtin_amdgcn_mfma_f32_16x16x32_bf16(
                        A[pf][kf], Bl[kf][jf], acc[pf][jf], 0, 0, 0);

        if (L < 4) {
            // relu -> LDS [e][j] bf16, then reload as next layer's A-frags
#pragma unroll
            for (int pf = 0; pf < 4; pf++)
#pragma unroll
                for (int jf = 0; jf < 4; jf++) {
                    const int j = jf * 16 + l15;
#pragma unroll
                    for (int r = 0; r < 4; r++)
                        my[(pf * 16 + l4 * 4 + r) * 72 + j] =
                            (__bf16)fmaxf(acc[pf][jf][r], 0.f);
                }
#pragma unroll
            for (int pf = 0; pf < 4; pf++)
#pragma unroll
                for (int kf = 0; kf < 2; kf++)
                    A[pf][kf] = *(const bf16x8*)(my + (pf * 16 + l15) * 72 +
                                                 kf * 32 + l4 * 8);
        } else {
            // final phi2 layer: relu, masked sum over events, atomic into s2
            float t[4];
#pragma unroll
            for (int jf = 0; jf < 4; jf++) {
                float s = 0.f;
#pragma unroll
                for (int pf = 0; pf < 4; pf++)
#pragma unroll
                    for (int r = 0; r < 4; r++) {
                        const int e = ebase + pf * 16 + l4 * 4 + r;
                        float v = fmaxf(acc[pf][jf][r], 0.f);
                        s += (e < NE) ? v : 0.f;
                    }
                s += __shfl_xor(s, 16);
                s += __shfl_xor(s, 32);
                t[jf] = s;
            }
            if (l < 16) {
#pragma unroll
                for (int jf = 0; jf < 4; jf++)
                    atomicAdd(s2 + jf * 16 + l, t[jf]);
            }
        }
    }
}

// ---------------- K3: rho2 + output + log_softmax (tiny) ----------------
__global__ __launch_bounds__(64) void k3_final(
    const float* __restrict__ s2,
    const float* __restrict__ W0, const float* __restrict__ B0,
    const float* __restrict__ W1, const float* __restrict__ B1,
    const float* __restrict__ W2, const float* __restrict__ B2,
    float* __restrict__ out) {
    __shared__ __align__(16) float xb[64];
    __shared__ __align__(16) float yb[64];
    __shared__ float ob[10];
    const int l = threadIdx.x;

    xb[l] = s2[l];
    __syncthreads();

    float a = B0[l];
#pragma unroll
    for (int k = 0; k < 16; k++) {
        fvec4 wv = *(const fvec4*)(W0 + l * 64 + k * 4);
        fvec4 xv = *(const fvec4*)(xb + k * 4);
        a += wv[0] * xv[0] + wv[1] * xv[1] + wv[2] * xv[2] + wv[3] * xv[3];
    }
    yb[l] = fmaxf(a, 0.f);
    __syncthreads();

    float b_ = B1[l];
#pragma unroll
    for (int k = 0; k < 16; k++) {
        fvec4 wv = *(const fvec4*)(W1 + l * 64 + k * 4);
        fvec4 xv = *(const fvec4*)(yb + k * 4);
        b_ += wv[0] * xv[0] + wv[1] * xv[1] + wv[2] * xv[2] + wv[3] * xv[3];
    }
    __syncthreads();          // everyone done reading xb (layer 1)
    xb[l] = fmaxf(b_, 0.f);
    __syncthreads();

    if (l < 10) {
        float o = B2[l];
#pragma unroll
        for (int k = 0; k < 16; k++) {
            fvec4 wv = *(const fvec4*)(W2 + l * 64 + k * 4);
            fvec4 xv = *(const fvec4*)(xb + k * 4);
            o += wv[0] * xv[0] + wv[1] * xv[1] + wv[2] * xv[2] + wv[3] * xv[3];
        }
        ob[l] = o;
    }
    __syncthreads();
    if (l == 0) {
        float m = ob[0];
#pragma unroll
        for (int i = 1; i < 10; i++) m = fmaxf(m, ob[i]);
        float sum = 0.f;
#pragma unroll
        for (int i = 0; i < 10; i++) sum = sum + expf(ob[i] - m);
        float ls = logf(sum);
#pragma unroll
        for (int i = 0; i < 10; i++) out[i] = ob[i] - m - ls;
    }
}

extern "C" void kernel_launch(void* const* d_in, const int* in_sizes, int n_in,
                              void* d_out, int out_size, void* d_ws, size_t ws_size,
                              hipStream_t stream) {
    const float* values = (const float*)d_in[0];
    const int*   seg    = (const int*)d_in[1];
    const float* p1w0 = (const float*)d_in[2],  *p1b0 = (const float*)d_in[3];
    const float* p1w1 = (const float*)d_in[4],  *p1b1 = (const float*)d_in[5];
    const float* r1w0 = (const float*)d_in[6],  *r1b0 = (const float*)d_in[7];
    const float* r1w1 = (const float*)d_in[8],  *r1b1 = (const float*)d_in[9];
    const float* o1w  = (const float*)d_in[10], *o1b  = (const float*)d_in[11];
    const float* p2w0 = (const float*)d_in[12], *p2b0 = (const float*)d_in[13];
    const float* p2w1 = (const float*)d_in[14], *p2b1 = (const float*)d_in[15];
    const float* r2w0 = (const float*)d_in[16], *r2b0 = (const float*)d_in[17];
    const float* r2w1 = (const float*)d_in[18], *r2b1 = (const float*)d_in[19];
    const float* o2w  = (const float*)d_in[20], *o2b  = (const float*)d_in[21];

    float* ev = (float*)d_ws;                       // [NE][64] accumulators
    float* s2 = ev + (size_t)NE * 64;               // [64]

    hipMemsetAsync(d_ws, 0, (size_t)(NE * 64 + 64) * sizeof(float), stream);

    hipLaunchKernelGGL(k1_phi1, dim3(2048), dim3(256), 0, stream,
                       values, seg, p1w0, p1b0, p1w1, p1b1, ev);
    hipLaunchKernelGGL(k2_events, dim3((NE + 255) / 256), dim3(256), 0, stream,
                       ev, r1w0, r1b0, r1w1, r1b1, o1w, o1b,
                       p2w0, p2b0, p2w1, p2b1, s2);
    hipLaunchKernelGGL(k3_final, dim3(1), dim3(64), 0, stream,
                       s2, r2w0, r2b0, r2w1, r2b1, o2w, o2b, (float*)d_out);
}